// Round 2
// baseline (9241.310 us; speedup 1.0000x reference)
//
#include <hip/hip_runtime.h>
#include <cstdint>

#define HH 384
#define TTC 32
#define NBINS 256

__device__ inline float4 ld4(const float* p){ return *(const float4*)p; }

// ---------------- pos = cumsum(x[...,0]!=0) * mask ----------------
__global__ __launch_bounds__(1024) void pos_kernel(const float* __restrict__ x,
    int* __restrict__ pos, int T)
{
  __shared__ int s[1024];
  int b = blockIdx.x, tid = threadIdx.x;
  int m = 0;
  if (tid < T) m = (x[((size_t)b*T + tid)*HH] != 0.f) ? 1 : 0;
  s[tid] = m;
  __syncthreads();
  for (int off = 1; off < 1024; off <<= 1){
    int add = (tid >= off) ? s[tid-off] : 0;
    __syncthreads();
    s[tid] += add;
    __syncthreads();
  }
  if (tid < T) pos[(size_t)b*T + tid] = s[tid] * m;
}

// ---------------- out = x + alpha * sinusoidal_pe(pos) ----------------
__global__ __launch_bounds__(HH) void add_pe_kernel(const float* __restrict__ x,
    const int* __restrict__ pos, const float* __restrict__ alpha,
    float* __restrict__ out)
{
  int row = blockIdx.x; int i = threadIdx.x;
  int p = pos[row];
  float pe = 0.f;
  if (p != 0){
    int j = (i < HH/2) ? i : i - HH/2;
    float inv = expf((float)j * -0.04822167734018944f); // -ln(10000)/191
    float ang = (float)p * inv;
    pe = (i < HH/2) ? sinf(ang) : cosf(ang);
  }
  out[(size_t)row*HH + i] = x[(size_t)row*HH + i] + alpha[0]*pe;
}

// ---------------- fused conv1d(same,K) + relu + LN(channels) + affine ----------------
template<int K>
__global__ __launch_bounds__(HH) void conv_ln_kernel(
    const float* __restrict__ in, const float* __restrict__ w,
    const float* __restrict__ bias, const float* __restrict__ g,
    const float* __restrict__ be, float* __restrict__ out, int T)
{
  constexpr int P = (K-1)/2;
  constexpr int R = TTC + K - 1;
  __shared__ float xs[R][HH];
  __shared__ float ps[6][TTC];
  __shared__ float pq[6][TTC];

  int ntile = T / TTC;
  int b  = blockIdx.x / ntile;
  int t0 = (blockIdx.x % ntile) * TTC;
  int o  = threadIdx.x;
  const float* inb = in + (size_t)b*T*HH;

  for (int r = 0; r < R; ++r){
    int t = t0 + r - P;
    xs[r][o] = (t >= 0 && t < T) ? inb[(size_t)t*HH + o] : 0.f;
  }
  __syncthreads();

  float acc[TTC];
  float bo = bias[o];
  #pragma unroll
  for (int t = 0; t < TTC; ++t) acc[t] = bo;

  const float* wrow = w + (size_t)o*HH*K;
  for (int i0 = 0; i0 < HH; i0 += 4){
    float wreg[4*K];
    const float* wp = wrow + i0*K;
    #pragma unroll
    for (int q = 0; q < K; ++q) *(float4*)(wreg + 4*q) = ld4(wp + 4*q);
    #pragma unroll
    for (int r = 0; r < R; ++r){
      float4 xv = ld4(&xs[r][i0]);
      float xa[4] = {xv.x, xv.y, xv.z, xv.w};
      #pragma unroll
      for (int di = 0; di < 4; ++di){
        #pragma unroll
        for (int k = 0; k < K; ++k){
          int t = r - k;
          if (t >= 0 && t < TTC)
            acc[t] = fmaf(xa[di], wreg[di*K + k], acc[t]);
        }
      }
    }
  }

  // relu
  #pragma unroll
  for (int t = 0; t < TTC; ++t) acc[t] = fmaxf(acc[t], 0.f);

  // LN over channels (across the 384 threads), per t
  int wid = threadIdx.x >> 6, lane = threadIdx.x & 63;
  #pragma unroll
  for (int t = 0; t < TTC; ++t){
    float s1 = acc[t], s2 = acc[t]*acc[t];
    #pragma unroll
    for (int off = 32; off; off >>= 1){
      s1 += __shfl_xor(s1, off);
      s2 += __shfl_xor(s2, off);
    }
    if (lane == 0){ ps[wid][t] = s1; pq[wid][t] = s2; }
  }
  __syncthreads();

  float gg = g[o], bb = be[o];
  #pragma unroll
  for (int t = 0; t < TTC; ++t){
    float s1 = 0.f, s2 = 0.f;
    #pragma unroll
    for (int ww = 0; ww < 6; ++ww){ s1 += ps[ww][t]; s2 += pq[ww][t]; }
    float m   = s1 * (1.f/HH);
    float var = fmaxf(s2 * (1.f/HH) - m*m, 0.f);
    float rr  = rsqrtf(var + 1e-5f);
    out[((size_t)b*T + t0 + t)*HH + o] = (acc[t] - m)*rr*gg + bb;
  }
}

// ---------------- pred = h @ lw + lb ; idx = searchsorted(bins, pred, 'left') ----------------
__global__ __launch_bounds__(256) void proj_var_kernel(const float* __restrict__ h,
    const float* __restrict__ lw, const float* __restrict__ lb,
    const float* __restrict__ bins, float* __restrict__ pred,
    int* __restrict__ idx, int nrows)
{
  int lane = threadIdx.x & 63, wid = threadIdx.x >> 6;
  int wave = blockIdx.x*4 + wid, nw = gridDim.x*4;
  float lwr[6];
  #pragma unroll
  for (int j = 0; j < 6; ++j) lwr[j] = lw[lane + 64*j];
  float lbv = lb[0];
  for (int row = wave; row < nrows; row += nw){
    const float* hr = h + (size_t)row*HH;
    float s = 0.f;
    #pragma unroll
    for (int j = 0; j < 6; ++j) s = fmaf(hr[lane + 64*j], lwr[j], s);
    #pragma unroll
    for (int off = 32; off; off >>= 1) s += __shfl_xor(s, off);
    if (lane == 0){
      float v = s + lbv;
      pred[row] = v;
      int lo = 0, hi = NBINS - 1;
      while (lo < hi){ int mid = (lo + hi) >> 1; if (bins[mid] < v) lo = mid + 1; else hi = mid; }
      idx[row] = lo;
    }
  }
}

// ---------------- log_d, dur (float), dur (int) ----------------
__global__ __launch_bounds__(256) void proj_dur_kernel(const float* __restrict__ h,
    const float* __restrict__ lw, const float* __restrict__ lb,
    const unsigned char* __restrict__ mask, float* __restrict__ logd,
    float* __restrict__ durf, int* __restrict__ duri, int nrows)
{
  int lane = threadIdx.x & 63, wid = threadIdx.x >> 6;
  int wave = blockIdx.x*4 + wid, nw = gridDim.x*4;
  float lwr[6];
  #pragma unroll
  for (int j = 0; j < 6; ++j) lwr[j] = lw[lane + 64*j];
  float lbv = lb[0];
  for (int row = wave; row < nrows; row += nw){
    const float* hr = h + (size_t)row*HH;
    float s = 0.f;
    #pragma unroll
    for (int j = 0; j < 6; ++j) s = fmaf(hr[lane + 64*j], lwr[j], s);
    #pragma unroll
    for (int off = 32; off; off >>= 1) s += __shfl_xor(s, off);
    if (lane == 0){
      float v = s + lbv;
      if (mask[row]) v = 0.f;
      logd[row] = v;
      float d = fmaxf(rintf(expf(v) - 1.f), 0.f);
      durf[row] = d;
      duri[row] = (int)d;
    }
  }
}

// ---------------- per-batch inclusive cumsum of dur, mel_len ----------------
__global__ __launch_bounds__(1024) void cumsum_kernel(const int* __restrict__ duri,
    int* __restrict__ cum, float* __restrict__ mel, int T, int ML)
{
  __shared__ int s[1024];
  int b = blockIdx.x, tid = threadIdx.x;
  s[tid] = (tid < T) ? duri[(size_t)b*T + tid] : 0;
  __syncthreads();
  for (int off = 1; off < 1024; off <<= 1){
    int add = (tid >= off) ? s[tid-off] : 0;
    __syncthreads();
    s[tid] += add;
    __syncthreads();
  }
  if (tid < T) cum[(size_t)b*T + tid] = s[tid];
  if (tid == T-1) mel[b] = (float)min(s[tid], ML);
}

// ---------------- x_adapt = x + pitch_table[ip] + energy_table[ie] ----------------
__global__ __launch_bounds__(256) void xadapt_kernel(const float* __restrict__ x,
    const int* __restrict__ ip, const int* __restrict__ ie,
    const float* __restrict__ pt, const float* __restrict__ et,
    float* __restrict__ xa, int nrows)
{
  int gid = blockIdx.x*256 + threadIdx.x;
  int n4 = nrows * (HH/4);
  if (gid >= n4) return;
  int row = gid / (HH/4);
  int c = gid - row*(HH/4);
  float4 xv = ((const float4*)x)[gid];
  const float4* pr = (const float4*)(pt + (size_t)ip[row]*HH);
  const float4* er = (const float4*)(et + (size_t)ie[row]*HH);
  float4 pv = pr[c], ev = er[c];
  ((float4*)xa)[gid] = make_float4(xv.x+pv.x+ev.x, xv.y+pv.y+ev.y,
                                   xv.z+pv.z+ev.z, xv.w+pv.w+ev.w);
}

// ---------------- length regulate: gather + zero-fill ----------------
__global__ __launch_bounds__(256) void lr_kernel(const float* __restrict__ xa,
    const int* __restrict__ cum, float* __restrict__ out, int T, int ML)
{
  constexpr int FR = 32;
  __shared__ int scum[1024];
  __shared__ int sidx[FR];
  __shared__ int svalid[FR];
  int b  = blockIdx.y;
  int f0 = blockIdx.x * FR;
  for (int i = threadIdx.x; i < T; i += 256) scum[i] = cum[(size_t)b*T + i];
  __syncthreads();
  int total = scum[T-1];
  if (threadIdx.x < FR){
    int f = f0 + threadIdx.x;
    int lo = 0, hi = T;
    while (lo < hi){ int mid = (lo + hi) >> 1; if (scum[mid] <= f) lo = mid + 1; else hi = mid; }
    sidx[threadIdx.x] = min(lo, T-1);
    svalid[threadIdx.x] = (f < total) ? 1 : 0;
  }
  __syncthreads();
  #pragma unroll
  for (int it = 0; it < FR*(HH/4)/256; ++it){
    int item = it*256 + threadIdx.x;
    int fl = item / (HH/4);
    int c  = item - fl*(HH/4);
    int f  = f0 + fl;
    if (f >= ML) continue;
    float4 v = make_float4(0.f,0.f,0.f,0.f);
    if (svalid[fl]) v = ((const float4*)(xa + ((size_t)b*T + sidx[fl])*HH))[c];
    ((float4*)(out + ((size_t)b*ML + f)*HH))[c] = v;
  }
}

extern "C" void kernel_launch(void* const* d_in, const int* in_sizes, int n_in,
                              void* d_out, int out_size, void* d_ws, size_t ws_size,
                              hipStream_t stream)
{
  const float* x        = (const float*)d_in[0];
  const unsigned char* src_mask = (const unsigned char*)d_in[2];
  const float* dp_w1 = (const float*)d_in[4];
  const float* dp_b1 = (const float*)d_in[5];
  const float* dp_g1 = (const float*)d_in[6];
  const float* dp_be1= (const float*)d_in[7];
  const float* dp_w2 = (const float*)d_in[8];
  const float* dp_b2 = (const float*)d_in[9];
  const float* dp_g2 = (const float*)d_in[10];
  const float* dp_be2= (const float*)d_in[11];
  const float* dp_lw = (const float*)d_in[12];
  const float* dp_lb = (const float*)d_in[13];
  const float* pp_cw = (const float*)d_in[14];
  const float* pp_cb = (const float*)d_in[15];
  const float* pp_g  = (const float*)d_in[16];
  const float* pp_b  = (const float*)d_in[17];
  const float* pp_lw = (const float*)d_in[18];
  const float* pp_lb = (const float*)d_in[19];
  const float* pp_alpha = (const float*)d_in[20];
  const float* ep_cw = (const float*)d_in[21];
  const float* ep_cb = (const float*)d_in[22];
  const float* ep_g  = (const float*)d_in[23];
  const float* ep_b  = (const float*)d_in[24];
  const float* ep_lw = (const float*)d_in[25];
  const float* ep_lb = (const float*)d_in[26];
  const float* ep_alpha = (const float*)d_in[27];
  const float* pbins = (const float*)d_in[28];
  const float* ebins = (const float*)d_in[29];
  const float* ptab  = (const float*)d_in[30];
  const float* etab  = (const float*)d_in[31];

  int B = in_sizes[1];
  int T = in_sizes[0] / (B*HH);
  int ML = (int)(((long long)out_size - B - 4LL*B*T) / ((long long)B*HH));
  size_t rows = (size_t)B*T;

  float* bufA = (float*)d_ws;
  float* bufB = bufA + rows*HH;
  int* pos    = (int*)(bufB + rows*HH);
  int* idx_p  = pos + rows;
  int* idx_e  = idx_p + rows;
  int* dur_i  = idx_e + rows;
  int* cum    = dur_i + rows;

  float* out0    = (float*)d_out;
  float* logd    = out0 + (size_t)B*ML*HH;
  float* durf    = logd + rows;
  float* pitchp  = durf + rows;
  float* energyp = pitchp + rows;
  float* mel     = energyp + rows;

  int conv_grid = B * (T / TTC);

  pos_kernel<<<B, 1024, 0, stream>>>(x, pos, T);

  // ---- pitch predictor: 5 conv layers ----
  add_pe_kernel<<<(int)rows, HH, 0, stream>>>(x, pos, pp_alpha, bufA);
  {
    float* src = bufA; float* dst = bufB;
    for (int l = 0; l < 5; ++l){
      conv_ln_kernel<5><<<conv_grid, HH, 0, stream>>>(src,
          pp_cw + (size_t)l*HH*HH*5, pp_cb + (size_t)l*HH,
          pp_g + (size_t)l*HH, pp_b + (size_t)l*HH, dst, T);
      float* t2 = dst; dst = src; src = t2;
    }
    proj_var_kernel<<<256, 256, 0, stream>>>(src, pp_lw, pp_lb, pbins,
                                             pitchp, idx_p, (int)rows);
  }

  // ---- energy predictor: 2 conv layers ----
  add_pe_kernel<<<(int)rows, HH, 0, stream>>>(x, pos, ep_alpha, bufA);
  {
    float* src = bufA; float* dst = bufB;
    for (int l = 0; l < 2; ++l){
      conv_ln_kernel<5><<<conv_grid, HH, 0, stream>>>(src,
          ep_cw + (size_t)l*HH*HH*5, ep_cb + (size_t)l*HH,
          ep_g + (size_t)l*HH, ep_b + (size_t)l*HH, dst, T);
      float* t2 = dst; dst = src; src = t2;
    }
    proj_var_kernel<<<256, 256, 0, stream>>>(src, ep_lw, ep_lb, ebins,
                                             energyp, idx_e, (int)rows);
  }

  // ---- duration predictor: 2 conv layers (k=3) ----
  conv_ln_kernel<3><<<conv_grid, HH, 0, stream>>>(x, dp_w1, dp_b1, dp_g1, dp_be1, bufB, T);
  conv_ln_kernel<3><<<conv_grid, HH, 0, stream>>>(bufB, dp_w2, dp_b2, dp_g2, dp_be2, bufA, T);
  proj_dur_kernel<<<256, 256, 0, stream>>>(bufA, dp_lw, dp_lb, src_mask,
                                           logd, durf, dur_i, (int)rows);

  cumsum_kernel<<<B, 1024, 0, stream>>>(dur_i, cum, mel, T, ML);

  xadapt_kernel<<<(int)((rows*(HH/4) + 255)/256), 256, 0, stream>>>(
      x, idx_p, idx_e, ptab, etab, bufB, (int)rows);

  lr_kernel<<<dim3(ML/32, B), 256, 0, stream>>>(bufB, cum, out0, T, ML);
}